// Round 18
// baseline (328.160 us; speedup 1.0000x reference)
//
#include <hip/hip_runtime.h>
#include <hip/hip_fp16.h>
#include <math.h>
#include <stdint.h>

// MSDeformAttn. N=2, C=256, M=8, L=4, P=4, D=32, LEN=21760
// R18: R17 with k_gather __launch_bounds__(256,6) — occupancy was capped at
//      30% by (256,3) while VGPR=64 supports 6 blocks/CU (cap 84).

constexpr int NB  = 2;
constexpr int C   = 256;
constexpr int M   = 8;
constexpr int D   = 32;
constexpr int LEN = 21760;
constexpr int QCHc = LEN / 2;   // 10880 queries per chunk (per batch)

typedef __attribute__((ext_vector_type(8))) short short8v;
typedef __attribute__((ext_vector_type(4))) float f32x4;

__device__ __forceinline__ short f2bf(float x) {
  uint32_t u = __float_as_uint(x);
  u = (u + 0x7fffu + ((u >> 16) & 1u)) >> 16;
  return (short)u;
}

// ---------------------------------------------------------------------------
// Weight prepack into per-fragment-coalesced layout:
// WP[((ks*NCG+cg)*64 + lane)*8 + e] = W[ks*32 + (lane>>4)*8 + e][cg*16 + (lane&15)]
// ---------------------------------------------------------------------------
__global__ __launch_bounds__(256) void k_wpack(
    const float* __restrict__ Wval, const float* __restrict__ Woff,
    const float* __restrict__ Wattn, const float* __restrict__ Wout,
    short* __restrict__ WvP, short* __restrict__ WdP, short* __restrict__ WoP) {
  const int job = blockIdx.y;
  const int ncols = (job == 1) ? 384 : 256;
  const int NCG = ncols / 16;
  const int elems = 256 * ncols;
  const int idx = blockIdx.x * 256 + threadIdx.x;
  if (idx >= elems) return;
  const int e    = idx & 7;
  const int lane = (idx >> 3) & 63;
  const int lr = lane & 15, lk = lane >> 4;
  const int cgks = idx >> 9;
  const int cg = cgks % NCG, ks = cgks / NCG;
  const int k = ks * 32 + lk * 8 + e;
  const int col = cg * 16 + lr;
  float v;
  if (job == 0)      v = Wval[(size_t)k * 256 + col];
  else if (job == 2) v = Wout[(size_t)k * 256 + col];
  else               v = (col < 256) ? Woff[(size_t)k * 256 + col]
                                     : Wattn[(size_t)k * 128 + col - 256];
  short* dst = (job == 0) ? WvP : (job == 1) ? WdP : WoP;
  dst[idx] = f2bf(v);
}

__device__ __forceinline__ short8v ldBP(const short* __restrict__ WP, int NCG,
                                        int cg, int ks, int lane) {
  const int4 v = *(const int4*)(WP + ((size_t)((ks * NCG + cg) * 64 + lane)) * 8);
  union { int4 i; short8v s; } u; u.i = v; return u.s;
}

// ---------------------------------------------------------------------------
// LDS staging (32 rows x 256 k, bf16, XOR-swizzled) + A fragment loads
// ---------------------------------------------------------------------------
__device__ __forceinline__ void stage_cast(const float* __restrict__ p, char* sm, int t) {
  const int r = t >> 3, seg = t & 7;
  const float4* s = (const float4*)(p + (size_t)r * C + seg * 32);
  short v[32];
#pragma unroll
  for (int i = 0; i < 8; ++i) {
    float4 f = s[i];
    v[i * 4 + 0] = f2bf(f.x); v[i * 4 + 1] = f2bf(f.y);
    v[i * 4 + 2] = f2bf(f.z); v[i * 4 + 3] = f2bf(f.w);
  }
#pragma unroll
  for (int i = 0; i < 4; ++i) {
    const int kb = (seg * 32 + i * 8) * 2;
    *(int4*)(sm + r * 512 + (kb ^ ((r & 7) << 4))) = ((const int4*)v)[i];
  }
}

__device__ __forceinline__ void stage_bf16(const short* __restrict__ p, char* sm, int t) {
  const int r = t >> 3, seg = t & 7;
  const int4* s = (const int4*)(p + (size_t)r * C + seg * 32);
#pragma unroll
  for (int i = 0; i < 4; ++i) {
    const int kb = (seg * 32 + i * 8) * 2;
    *(int4*)(sm + r * 512 + (kb ^ ((r & 7) << 4))) = s[i];
  }
}

__device__ __forceinline__ short8v ldsA(const char* sm, int lane, int rt, int ks) {
  const int row = rt * 16 + (lane & 15);
  const int kb  = ks * 64 + ((lane >> 4) << 4);
  const int4 v = *(const int4*)(sm + row * 512 + (kb ^ ((row & 7) << 4)));
  union { int4 i; short8v s; } u; u.i = v; return u.s;
}

#define MFMA __builtin_amdgcn_mfma_f32_16x16x32_bf16

// ---------------------------------------------------------------------------
// GEMM body shared by valproj/outproj (proven in R10)
// ---------------------------------------------------------------------------
#define GEMM_BODY(WP)                                                       \
  short8v a[2][8];                                                          \
  _Pragma("unroll") for (int rt = 0; rt < 2; ++rt)                          \
  _Pragma("unroll") for (int ks = 0; ks < 8; ++ks)                          \
      a[rt][ks] = ldsA(smA, lane, rt, ks);                                  \
  f32x4 acc[2][4];                                                          \
  _Pragma("unroll") for (int rt = 0; rt < 2; ++rt)                          \
  _Pragma("unroll") for (int ct = 0; ct < 4; ++ct)                          \
      acc[rt][ct] = (f32x4){0.f, 0.f, 0.f, 0.f};                            \
  short8v b0[8], b1[8];                                                     \
  _Pragma("unroll") for (int ks = 0; ks < 8; ++ks)                          \
      b0[ks] = ldBP(WP, 16, cg0 + 0, ks, lane);                             \
  _Pragma("unroll") for (int ks = 0; ks < 8; ++ks)                          \
      b1[ks] = ldBP(WP, 16, cg0 + 1, ks, lane);                             \
  _Pragma("unroll") for (int ks = 0; ks < 8; ++ks) {                        \
    acc[0][0] = MFMA(a[0][ks], b0[ks], acc[0][0], 0, 0, 0);                 \
    acc[1][0] = MFMA(a[1][ks], b0[ks], acc[1][0], 0, 0, 0);                 \
  }                                                                         \
  _Pragma("unroll") for (int ks = 0; ks < 8; ++ks)                          \
      b0[ks] = ldBP(WP, 16, cg0 + 2, ks, lane);                             \
  _Pragma("unroll") for (int ks = 0; ks < 8; ++ks) {                        \
    acc[0][1] = MFMA(a[0][ks], b1[ks], acc[0][1], 0, 0, 0);                 \
    acc[1][1] = MFMA(a[1][ks], b1[ks], acc[1][1], 0, 0, 0);                 \
  }                                                                         \
  _Pragma("unroll") for (int ks = 0; ks < 8; ++ks)                          \
      b1[ks] = ldBP(WP, 16, cg0 + 3, ks, lane);                             \
  _Pragma("unroll") for (int ks = 0; ks < 8; ++ks) {                        \
    acc[0][2] = MFMA(a[0][ks], b0[ks], acc[0][2], 0, 0, 0);                 \
    acc[1][2] = MFMA(a[1][ks], b0[ks], acc[1][2], 0, 0, 0);                 \
  }                                                                         \
  _Pragma("unroll") for (int ks = 0; ks < 8; ++ks) {                        \
    acc[0][3] = MFMA(a[0][ks], b1[ks], acc[0][3], 0, 0, 0);                 \
    acc[1][3] = MFMA(a[1][ks], b1[ks], acc[1][3], 0, 0, 0);                 \
  }

// ---------------------------------------------------------------------------
// Kernel: value = bf16mm(input_flatten, WvP) + bv -> fp16 value[n][m][pix][d]
// ---------------------------------------------------------------------------
__global__ __launch_bounds__(256, 2) void k_valproj(
    const float* __restrict__ infl, const short* __restrict__ WvP,
    const float* __restrict__ bv, __half* __restrict__ value) {
  __shared__ __align__(16) char smA[16384];
  const int t = threadIdx.x, lane = t & 63, w = t >> 6;
  const int r0 = blockIdx.x * 32;
  stage_cast(infl + (size_t)r0 * C, smA, t);
  __syncthreads();
  const int cg0 = w * 4;
  const int lr = lane & 15, lk = lane >> 4;
  GEMM_BODY(WvP)

  const int n = (blockIdx.x >= (LEN / 32)) ? 1 : 0;
  const int pixbase = r0 - n * LEN;
#pragma unroll
  for (int ct = 0; ct < 4; ++ct) {
    const int col = (cg0 + ct) * 16 + lr;
    const float bb = bv[col];
    const int m = col >> 5, d = col & 31;
    __half* vp = value + ((size_t)(n * 8 + m) * LEN) * 32 + d;
#pragma unroll
    for (int rt = 0; rt < 2; ++rt)
#pragma unroll
      for (int r = 0; r < 4; ++r) {
        const int pix = pixbase + rt * 16 + lk * 4 + r;
        vp[(size_t)pix * 32] = __float2half(acc[rt][ct][r] + bb);
      }
  }
}

// ---------------------------------------------------------------------------
// Kernel: out = bf16mm(accB, WoP) + bo (fp32 out)
// ---------------------------------------------------------------------------
__global__ __launch_bounds__(256, 2) void k_outproj(
    const short* __restrict__ accB, const short* __restrict__ WoP,
    const float* __restrict__ bo, float* __restrict__ out) {
  __shared__ __align__(16) char smA[16384];
  const int t = threadIdx.x, lane = t & 63, w = t >> 6;
  const int r0 = blockIdx.x * 32;
  stage_bf16(accB + (size_t)r0 * C, smA, t);
  __syncthreads();
  const int cg0 = w * 4;
  const int lr = lane & 15, lk = lane >> 4;
  GEMM_BODY(WoP)

#pragma unroll
  for (int ct = 0; ct < 4; ++ct) {
    const int col = (cg0 + ct) * 16 + lr;
    const float bb = bo[col];
#pragma unroll
    for (int rt = 0; rt < 2; ++rt)
#pragma unroll
      for (int r = 0; r < 4; ++r) {
        const int row = r0 + rt * 16 + lk * 4 + r;
        out[(size_t)row * C + col] = acc[rt][ct][r] + bb;
      }
  }
}

// ---------------------------------------------------------------------------
// Kernel: offsets/attn GEMM + softmax + 8B fixed-point descriptor build
// descD[((n*8+m)*QCHc + q)*16 + j] : uint2 {xfix|(yfix<<16), aw_half}
// fixed point: (coord + 8) * 128, coord clamped to [-8, 503]
// ---------------------------------------------------------------------------
__global__ __launch_bounds__(256, 3) void k_desc(
    const float* __restrict__ query, const float* __restrict__ refp,
    const short* __restrict__ WdP, const float* __restrict__ boff,
    const float* __restrict__ battn, uint2* __restrict__ descD, int qbase) {
  __shared__ __align__(16) char smem[50176];
  char*  smA  = smem;                       // [32][512] bf16 A-tile
  float* offs = (float*)smem;               // [32][256] (aliases smA; used later)
  float* attw = (float*)(smem + 32768);     // [32][128]
  float* refs = (float*)(smem + 49152);     // [32][8]

  const int t = threadIdx.x, lane = t & 63, w = t >> 6;
  const int n   = blockIdx.x / 340;
  const int q0c = (blockIdx.x % 340) * 32;
  const size_t qrow = (size_t)n * LEN + qbase + q0c;

  refs[t] = refp[qrow * 8 + t];
  stage_cast(query + qrow * C, smA, t);
  __syncthreads();

  f32x4 acc[2][6];
#pragma unroll
  for (int a = 0; a < 2; ++a)
#pragma unroll
    for (int b = 0; b < 6; ++b) acc[a][b] = (f32x4){0.f, 0.f, 0.f, 0.f};
  const int cgb = w * 6;
#pragma unroll
  for (int ks = 0; ks < 8; ++ks) {
    const short8v a0 = ldsA(smA, lane, 0, ks);
    const short8v a1 = ldsA(smA, lane, 1, ks);
#pragma unroll
    for (int ct = 0; ct < 6; ++ct) {
      const short8v b = ldBP(WdP, 24, cgb + ct, ks, lane);
      acc[0][ct] = MFMA(a0, b, acc[0][ct], 0, 0, 0);
      acc[1][ct] = MFMA(a1, b, acc[1][ct], 0, 0, 0);
    }
  }
  __syncthreads();   // all LDS A reads complete before aliasing writes

#pragma unroll
  for (int ct = 0; ct < 6; ++ct) {
    const int col = (cgb + ct) * 16 + (lane & 15);
    const float bb = (col < 256) ? boff[col] : battn[col - 256];
#pragma unroll
    for (int rt = 0; rt < 2; ++rt)
#pragma unroll
      for (int r = 0; r < 4; ++r) {
        const int row = rt * 16 + ((lane >> 4) << 2) + r;
        const float vv = acc[rt][ct][r] + bb;
        if (col < 256) offs[row * 256 + col] = vv;
        else           attw[row * 128 + col - 256] = vv;
      }
  }
  __syncthreads();

  // softmax over 16 per (q, m): 256 tasks
  {
    const int q = t >> 3, m = t & 7;
    float v[16], mx = -1e30f;
#pragma unroll
    for (int j = 0; j < 16; ++j) { v[j] = attw[q * 128 + m * 16 + j]; mx = fmaxf(mx, v[j]); }
    float s = 0.f;
#pragma unroll
    for (int j = 0; j < 16; ++j) { v[j] = __expf(v[j] - mx); s += v[j]; }
    const float inv = 1.f / s;
#pragma unroll
    for (int j = 0; j < 16; ++j) attw[q * 128 + m * 16 + j] = v[j] * inv;
  }
  __syncthreads();

  // descriptor build: 32 q x 128 (m,j) = 4096, 16 per thread, coalesced
#pragma unroll
  for (int i = 0; i < 16; ++i) {
    const int e = i * 256 + t;
    const int q = e >> 7, rem = e & 127;
    const int m = rem >> 4, j = rem & 15, l = j >> 2;
    const int jo = m * 16 + j;
    const float ox = offs[q * 256 + 2 * jo], oy = offs[q * 256 + 2 * jo + 1];
    const float aw = attw[q * 128 + jo];
    const float rx = refs[q * 8 + l * 2 + 0], ry = refs[q * 8 + l * 2 + 1];
    const int W = 128 >> l;
    const float x = rx * (float)W + ox - 0.5f;
    const float y = ry * (float)W + oy - 0.5f;
    const float xc = fminf(fmaxf(x, -8.f), 503.f);
    const float yc = fminf(fmaxf(y, -8.f), 503.f);
    const uint32_t xfix = (uint32_t)((xc + 8.f) * 128.f + 0.5f);
    const uint32_t yfix = (uint32_t)((yc + 8.f) * 128.f + 0.5f);
    uint2 dsc;
    dsc.x = xfix | (yfix << 16);
    dsc.y = (uint32_t)__half_as_ushort(__float2half_rn(aw));
    descD[((size_t)(n * 8 + m) * QCHc + q0c + q) * 16 + j] = dsc;
  }
}

// ---------------------------------------------------------------------------
// Kernel: cross-group pipelined gather (R17) at 6 blocks/CU.
// ---------------------------------------------------------------------------
__global__ __launch_bounds__(256, 6) void k_gather(
    const uint2* __restrict__ descD, const __half* __restrict__ value,
    short* __restrict__ accB, int qbase) {
  const int t = threadIdx.x;
  const int d4 = t & 3, ql = t >> 2;          // 64 queries per block
  const int bid = blockIdx.x;
  const int s = bid & 15, qc = bid >> 4;      // slice, query-chunk (170)
  const int n = s >> 3, m = s & 7;
  const int q = qc * 64 + ql;                 // within chunk
  const uint4* dp4 = (const uint4*)(descD + ((size_t)(n * 8 + m) * QCHc + q) * 16);
  const char* vb = (const char*)value +
                   (size_t)((n * 8 + m) * LEN) * 64 + d4 * 16;

  uint4 dd[8];
#pragma unroll
  for (int i = 0; i < 8; ++i) dd[i] = dp4[i];
  __builtin_amdgcn_sched_barrier(0);

  float accf[8];
#pragma unroll
  for (int i = 0; i < 8; ++i) accf[i] = 0.f;

  union V { uint4 v; __half2 h[4]; };
  V rA[8], rB[8];
  __half2 hwA[8], hwB[8];

#define DECJ(G, ODD, R, HW, BASE)                                             \
  {                                                                           \
    constexpr int l_ = (G) >> 1;                                              \
    constexpr int W_ = 128 >> l_;                                             \
    constexpr int stl_ = (l_ == 0) ? 0 : (l_ == 1) ? 16384 : (l_ == 2) ? 20480 : 21504; \
    const uint32_t lo_ = (ODD) ? dd[G].z : dd[G].x;                           \
    const uint32_t hi_ = (ODD) ? dd[G].w : dd[G].y;                           \
    const int xf_ = (int)(lo_ & 0xffffu), yf_ = (int)(lo_ >> 16);             \
    const float aw_ = __half2float(__ushort_as_half((unsigned short)(hi_ & 0xffffu))); \
    const int xi_ = (xf_ >> 7) - 8, yi_ = (yf_ >> 7) - 8;                     \
    const float fx_ = (float)(xf_ & 127) * 0.0078125f;                        \
    const float fy_ = (float)(yf_ & 127) * 0.0078125f;                        \
    float wx0_ = 1.f - fx_, wx1_ = fx_, wy0_ = 1.f - fy_, wy1_ = fy_;         \
    if (xi_ < 0 || xi_ >= W_)         wx0_ = 0.f;                             \
    if (xi_ + 1 < 0 || xi_ + 1 >= W_) wx1_ = 0.f;                             \
    if (yi_ < 0 || yi_ >= W_)         wy0_ = 0.f;                             \
    if (yi_ + 1 < 0 || yi_ + 1 >= W_) wy1_ = 0.f;                             \
    const int x0_ = min(max(xi_, 0), W_ - 1), x1_ = min(max(xi_ + 1, 0), W_ - 1); \
    const int y0_ = min(max(yi_, 0), W_ - 1), y1_ = min(max(yi_ + 1, 0), W_ - 1); \
    HW[(BASE) + 0] = __float2half2_rn(wx0_ * wy0_ * aw_);                     \
    HW[(BASE) + 1] = __float2half2_rn(wx1_ * wy0_ * aw_);                     \
    HW[(BASE) + 2] = __float2half2_rn(wx0_ * wy1_ * aw_);                     \
    HW[(BASE) + 3] = __float2half2_rn(wx1_ * wy1_ * aw_);                     \
    R[(BASE) + 0].v = *(const uint4*)(vb + (size_t)(stl_ + y0_ * W_ + x0_) * 64u); \
    R[(BASE) + 1].v = *(const uint4*)(vb + (size_t)(stl_ + y0_ * W_ + x1_) * 64u); \
    R[(BASE) + 2].v = *(const uint4*)(vb + (size_t)(stl_ + y1_ * W_ + x0_) * 64u); \
    R[(BASE) + 3].v = *(const uint4*)(vb + (size_t)(stl_ + y1_ * W_ + x1_) * 64u); \
  }

#define DECG(G, R, HW)                                                        \
  DECJ(G, 0, R, HW, 0)                                                        \
  DECJ(G, 1, R, HW, 4)                                                        \
  __builtin_amdgcn_sched_barrier(0);

#define CONSG(R, HW)                                                          \
  {                                                                           \
    __half2 acch[4];                                                          \
    _Pragma("unroll") for (int i_ = 0; i_ < 4; ++i_)                          \
        acch[i_] = __float2half2_rn(0.f);                                     \
    _Pragma("unroll") for (int c_ = 0; c_ < 8; ++c_) {                        \
      _Pragma("unroll") for (int i_ = 0; i_ < 4; ++i_)                        \
          acch[i_] = __hfma2(R[c_].h[i_], HW[c_], acch[i_]);                  \
    }                                                                         \
    _Pragma("unroll") for (int i_ = 0; i_ < 4; ++i_) {                        \
      const float2 f_ = __half22float2(acch[i_]);                             \
      accf[2 * i_] += f_.x; accf[2 * i_ + 1] += f_.y;                         \
    }                                                                         \
  }

  DECG(0, rA, hwA)
  DECG(1, rB, hwB)
  CONSG(rA, hwA)
  DECG(2, rA, hwA)
  CONSG(rB, hwB)
  DECG(3, rB, hwB)
  CONSG(rA, hwA)
  DECG(4, rA, hwA)
  CONSG(rB, hwB)
  DECG(5, rB, hwB)
  CONSG(rA, hwA)
  DECG(6, rA, hwA)
  CONSG(rB, hwB)
  DECG(7, rB, hwB)
  CONSG(rA, hwA)
  CONSG(rB, hwB)
#undef DECJ
#undef DECG
#undef CONSG

  short8v o;
#pragma unroll
  for (int i = 0; i < 8; ++i) o[i] = f2bf(accf[i]);
  *(short8v*)(accB + ((size_t)n * LEN + qbase + q) * 256 + m * 32 + d4 * 8) = o;
}

// ---------------------------------------------------------------------------
extern "C" void kernel_launch(void* const* d_in, const int* in_sizes, int n_in,
                              void* d_out, int out_size, void* d_ws, size_t ws_size,
                              hipStream_t stream) {
  const float* query = (const float*)d_in[0];
  const float* refp  = (const float*)d_in[1];
  const float* infl  = (const float*)d_in[2];
  const float* Woff  = (const float*)d_in[3];
  const float* boff  = (const float*)d_in[4];
  const float* Wattn = (const float*)d_in[5];
  const float* battn = (const float*)d_in[6];
  const float* Wval  = (const float*)d_in[7];
  const float* bval  = (const float*)d_in[8];
  const float* Wout  = (const float*)d_in[9];
  const float* bout  = (const float*)d_in[10];
  float* out = (float*)d_out;

  char* ws = (char*)d_ws;
  __half* value = (__half*)ws;                   // 22,282,240 B
  short*  accB  = (short*)(ws + 22282240);       // 22,282,240 B
  uint2*  desc8 = (uint2*)(ws + 44564480);       // 22,282,240 B (one chunk)
  short*  WvP   = (short*)(ws + 66846720);       // 131,072 B
  short*  WdP   = (short*)(ws + 66977792);       // 196,608 B
  short*  WoP   = (short*)(ws + 67174400);       // 131,072 B  (total 67.3 MB)

  k_wpack<<<dim3(384, 3), 256, 0, stream>>>(Wval, Woff, Wattn, Wout,
                                            WvP, WdP, WoP);

  k_valproj<<<(NB * LEN) / 32, 256, 0, stream>>>(infl, WvP, bval, value);

  for (int c = 0; c < 2; ++c) {
    k_desc<<<NB * (QCHc / 32), 256, 0, stream>>>(query, refp, WdP, boff, battn,
                                                 desc8, c * QCHc);
    k_gather<<<16 * (QCHc / 64), 256, 0, stream>>>(desc8, value, accB, c * QCHc);
  }

  k_outproj<<<(NB * LEN) / 32, 256, 0, stream>>>(accB, WoP, bout, out);
}

// Round 19
// 156.758 us; speedup vs baseline: 2.0934x; 2.0934x over previous
//
#include <hip/hip_runtime.h>
#include <hip/hip_fp16.h>
#include <math.h>
#include <stdint.h>

// MSDeformAttn. N=2, C=256, M=8, L=4, P=4, D=32, LEN=21760
// R19: R17 gather (fence-pinned pipeline, VGPR=64) at LB(256,4) — cap 128
//      VGPR leaves codegen untouched (R18's LB(256,6) squeezed to 40 and
//      spilled: FETCH 24->220MB). Everything else = R16/R17 proven state.

constexpr int NB  = 2;
constexpr int C   = 256;
constexpr int M   = 8;
constexpr int D   = 32;
constexpr int LEN = 21760;
constexpr int QCHc = LEN / 2;   // 10880 queries per chunk (per batch)

typedef __attribute__((ext_vector_type(8))) short short8v;
typedef __attribute__((ext_vector_type(4))) float f32x4;

__device__ __forceinline__ short f2bf(float x) {
  uint32_t u = __float_as_uint(x);
  u = (u + 0x7fffu + ((u >> 16) & 1u)) >> 16;
  return (short)u;
}

// ---------------------------------------------------------------------------
// Weight prepack into per-fragment-coalesced layout:
// WP[((ks*NCG+cg)*64 + lane)*8 + e] = W[ks*32 + (lane>>4)*8 + e][cg*16 + (lane&15)]
// ---------------------------------------------------------------------------
__global__ __launch_bounds__(256) void k_wpack(
    const float* __restrict__ Wval, const float* __restrict__ Woff,
    const float* __restrict__ Wattn, const float* __restrict__ Wout,
    short* __restrict__ WvP, short* __restrict__ WdP, short* __restrict__ WoP) {
  const int job = blockIdx.y;
  const int ncols = (job == 1) ? 384 : 256;
  const int NCG = ncols / 16;
  const int elems = 256 * ncols;
  const int idx = blockIdx.x * 256 + threadIdx.x;
  if (idx >= elems) return;
  const int e    = idx & 7;
  const int lane = (idx >> 3) & 63;
  const int lr = lane & 15, lk = lane >> 4;
  const int cgks = idx >> 9;
  const int cg = cgks % NCG, ks = cgks / NCG;
  const int k = ks * 32 + lk * 8 + e;
  const int col = cg * 16 + lr;
  float v;
  if (job == 0)      v = Wval[(size_t)k * 256 + col];
  else if (job == 2) v = Wout[(size_t)k * 256 + col];
  else               v = (col < 256) ? Woff[(size_t)k * 256 + col]
                                     : Wattn[(size_t)k * 128 + col - 256];
  short* dst = (job == 0) ? WvP : (job == 1) ? WdP : WoP;
  dst[idx] = f2bf(v);
}

__device__ __forceinline__ short8v ldBP(const short* __restrict__ WP, int NCG,
                                        int cg, int ks, int lane) {
  const int4 v = *(const int4*)(WP + ((size_t)((ks * NCG + cg) * 64 + lane)) * 8);
  union { int4 i; short8v s; } u; u.i = v; return u.s;
}

// ---------------------------------------------------------------------------
// LDS staging (32 rows x 256 k, bf16, XOR-swizzled) + A fragment loads
// ---------------------------------------------------------------------------
__device__ __forceinline__ void stage_cast(const float* __restrict__ p, char* sm, int t) {
  const int r = t >> 3, seg = t & 7;
  const float4* s = (const float4*)(p + (size_t)r * C + seg * 32);
  short v[32];
#pragma unroll
  for (int i = 0; i < 8; ++i) {
    float4 f = s[i];
    v[i * 4 + 0] = f2bf(f.x); v[i * 4 + 1] = f2bf(f.y);
    v[i * 4 + 2] = f2bf(f.z); v[i * 4 + 3] = f2bf(f.w);
  }
#pragma unroll
  for (int i = 0; i < 4; ++i) {
    const int kb = (seg * 32 + i * 8) * 2;
    *(int4*)(sm + r * 512 + (kb ^ ((r & 7) << 4))) = ((const int4*)v)[i];
  }
}

__device__ __forceinline__ void stage_bf16(const short* __restrict__ p, char* sm, int t) {
  const int r = t >> 3, seg = t & 7;
  const int4* s = (const int4*)(p + (size_t)r * C + seg * 32);
#pragma unroll
  for (int i = 0; i < 4; ++i) {
    const int kb = (seg * 32 + i * 8) * 2;
    *(int4*)(sm + r * 512 + (kb ^ ((r & 7) << 4))) = s[i];
  }
}

__device__ __forceinline__ short8v ldsA(const char* sm, int lane, int rt, int ks) {
  const int row = rt * 16 + (lane & 15);
  const int kb  = ks * 64 + ((lane >> 4) << 4);
  const int4 v = *(const int4*)(sm + row * 512 + (kb ^ ((row & 7) << 4)));
  union { int4 i; short8v s; } u; u.i = v; return u.s;
}

#define MFMA __builtin_amdgcn_mfma_f32_16x16x32_bf16

// ---------------------------------------------------------------------------
// GEMM body shared by valproj/outproj (proven in R10)
// ---------------------------------------------------------------------------
#define GEMM_BODY(WP)                                                       \
  short8v a[2][8];                                                          \
  _Pragma("unroll") for (int rt = 0; rt < 2; ++rt)                          \
  _Pragma("unroll") for (int ks = 0; ks < 8; ++ks)                          \
      a[rt][ks] = ldsA(smA, lane, rt, ks);                                  \
  f32x4 acc[2][4];                                                          \
  _Pragma("unroll") for (int rt = 0; rt < 2; ++rt)                          \
  _Pragma("unroll") for (int ct = 0; ct < 4; ++ct)                          \
      acc[rt][ct] = (f32x4){0.f, 0.f, 0.f, 0.f};                            \
  short8v b0[8], b1[8];                                                     \
  _Pragma("unroll") for (int ks = 0; ks < 8; ++ks)                          \
      b0[ks] = ldBP(WP, 16, cg0 + 0, ks, lane);                             \
  _Pragma("unroll") for (int ks = 0; ks < 8; ++ks)                          \
      b1[ks] = ldBP(WP, 16, cg0 + 1, ks, lane);                             \
  _Pragma("unroll") for (int ks = 0; ks < 8; ++ks) {                        \
    acc[0][0] = MFMA(a[0][ks], b0[ks], acc[0][0], 0, 0, 0);                 \
    acc[1][0] = MFMA(a[1][ks], b0[ks], acc[1][0], 0, 0, 0);                 \
  }                                                                         \
  _Pragma("unroll") for (int ks = 0; ks < 8; ++ks)                          \
      b0[ks] = ldBP(WP, 16, cg0 + 2, ks, lane);                             \
  _Pragma("unroll") for (int ks = 0; ks < 8; ++ks) {                        \
    acc[0][1] = MFMA(a[0][ks], b1[ks], acc[0][1], 0, 0, 0);                 \
    acc[1][1] = MFMA(a[1][ks], b1[ks], acc[1][1], 0, 0, 0);                 \
  }                                                                         \
  _Pragma("unroll") for (int ks = 0; ks < 8; ++ks)                          \
      b1[ks] = ldBP(WP, 16, cg0 + 3, ks, lane);                             \
  _Pragma("unroll") for (int ks = 0; ks < 8; ++ks) {                        \
    acc[0][2] = MFMA(a[0][ks], b0[ks], acc[0][2], 0, 0, 0);                 \
    acc[1][2] = MFMA(a[1][ks], b0[ks], acc[1][2], 0, 0, 0);                 \
  }                                                                         \
  _Pragma("unroll") for (int ks = 0; ks < 8; ++ks) {                        \
    acc[0][3] = MFMA(a[0][ks], b1[ks], acc[0][3], 0, 0, 0);                 \
    acc[1][3] = MFMA(a[1][ks], b1[ks], acc[1][3], 0, 0, 0);                 \
  }

// ---------------------------------------------------------------------------
// Kernel: value = bf16mm(input_flatten, WvP) + bv -> fp16 value[n][m][pix][d]
// ---------------------------------------------------------------------------
__global__ __launch_bounds__(256, 2) void k_valproj(
    const float* __restrict__ infl, const short* __restrict__ WvP,
    const float* __restrict__ bv, __half* __restrict__ value) {
  __shared__ __align__(16) char smA[16384];
  const int t = threadIdx.x, lane = t & 63, w = t >> 6;
  const int r0 = blockIdx.x * 32;
  stage_cast(infl + (size_t)r0 * C, smA, t);
  __syncthreads();
  const int cg0 = w * 4;
  const int lr = lane & 15, lk = lane >> 4;
  GEMM_BODY(WvP)

  const int n = (blockIdx.x >= (LEN / 32)) ? 1 : 0;
  const int pixbase = r0 - n * LEN;
#pragma unroll
  for (int ct = 0; ct < 4; ++ct) {
    const int col = (cg0 + ct) * 16 + lr;
    const float bb = bv[col];
    const int m = col >> 5, d = col & 31;
    __half* vp = value + ((size_t)(n * 8 + m) * LEN) * 32 + d;
#pragma unroll
    for (int rt = 0; rt < 2; ++rt)
#pragma unroll
      for (int r = 0; r < 4; ++r) {
        const int pix = pixbase + rt * 16 + lk * 4 + r;
        vp[(size_t)pix * 32] = __float2half(acc[rt][ct][r] + bb);
      }
  }
}

// ---------------------------------------------------------------------------
// Kernel: out = bf16mm(accB, WoP) + bo (fp32 out)
// ---------------------------------------------------------------------------
__global__ __launch_bounds__(256, 2) void k_outproj(
    const short* __restrict__ accB, const short* __restrict__ WoP,
    const float* __restrict__ bo, float* __restrict__ out) {
  __shared__ __align__(16) char smA[16384];
  const int t = threadIdx.x, lane = t & 63, w = t >> 6;
  const int r0 = blockIdx.x * 32;
  stage_bf16(accB + (size_t)r0 * C, smA, t);
  __syncthreads();
  const int cg0 = w * 4;
  const int lr = lane & 15, lk = lane >> 4;
  GEMM_BODY(WoP)

#pragma unroll
  for (int ct = 0; ct < 4; ++ct) {
    const int col = (cg0 + ct) * 16 + lr;
    const float bb = bo[col];
#pragma unroll
    for (int rt = 0; rt < 2; ++rt)
#pragma unroll
      for (int r = 0; r < 4; ++r) {
        const int row = r0 + rt * 16 + lk * 4 + r;
        out[(size_t)row * C + col] = acc[rt][ct][r] + bb;
      }
  }
}

// ---------------------------------------------------------------------------
// Kernel: offsets/attn GEMM + softmax + 8B fixed-point descriptor build
// descD[((n*8+m)*QCHc + q)*16 + j] : uint2 {xfix|(yfix<<16), aw_half}
// fixed point: (coord + 8) * 128, coord clamped to [-8, 503]
// ---------------------------------------------------------------------------
__global__ __launch_bounds__(256, 3) void k_desc(
    const float* __restrict__ query, const float* __restrict__ refp,
    const short* __restrict__ WdP, const float* __restrict__ boff,
    const float* __restrict__ battn, uint2* __restrict__ descD, int qbase) {
  __shared__ __align__(16) char smem[50176];
  char*  smA  = smem;                       // [32][512] bf16 A-tile
  float* offs = (float*)smem;               // [32][256] (aliases smA; used later)
  float* attw = (float*)(smem + 32768);     // [32][128]
  float* refs = (float*)(smem + 49152);     // [32][8]

  const int t = threadIdx.x, lane = t & 63, w = t >> 6;
  const int n   = blockIdx.x / 340;
  const int q0c = (blockIdx.x % 340) * 32;
  const size_t qrow = (size_t)n * LEN + qbase + q0c;

  refs[t] = refp[qrow * 8 + t];
  stage_cast(query + qrow * C, smA, t);
  __syncthreads();

  f32x4 acc[2][6];
#pragma unroll
  for (int a = 0; a < 2; ++a)
#pragma unroll
    for (int b = 0; b < 6; ++b) acc[a][b] = (f32x4){0.f, 0.f, 0.f, 0.f};
  const int cgb = w * 6;
#pragma unroll
  for (int ks = 0; ks < 8; ++ks) {
    const short8v a0 = ldsA(smA, lane, 0, ks);
    const short8v a1 = ldsA(smA, lane, 1, ks);
#pragma unroll
    for (int ct = 0; ct < 6; ++ct) {
      const short8v b = ldBP(WdP, 24, cgb + ct, ks, lane);
      acc[0][ct] = MFMA(a0, b, acc[0][ct], 0, 0, 0);
      acc[1][ct] = MFMA(a1, b, acc[1][ct], 0, 0, 0);
    }
  }
  __syncthreads();   // all LDS A reads complete before aliasing writes

#pragma unroll
  for (int ct = 0; ct < 6; ++ct) {
    const int col = (cgb + ct) * 16 + (lane & 15);
    const float bb = (col < 256) ? boff[col] : battn[col - 256];
#pragma unroll
    for (int rt = 0; rt < 2; ++rt)
#pragma unroll
      for (int r = 0; r < 4; ++r) {
        const int row = rt * 16 + ((lane >> 4) << 2) + r;
        const float vv = acc[rt][ct][r] + bb;
        if (col < 256) offs[row * 256 + col] = vv;
        else           attw[row * 128 + col - 256] = vv;
      }
  }
  __syncthreads();

  // softmax over 16 per (q, m): 256 tasks
  {
    const int q = t >> 3, m = t & 7;
    float v[16], mx = -1e30f;
#pragma unroll
    for (int j = 0; j < 16; ++j) { v[j] = attw[q * 128 + m * 16 + j]; mx = fmaxf(mx, v[j]); }
    float s = 0.f;
#pragma unroll
    for (int j = 0; j < 16; ++j) { v[j] = __expf(v[j] - mx); s += v[j]; }
    const float inv = 1.f / s;
#pragma unroll
    for (int j = 0; j < 16; ++j) attw[q * 128 + m * 16 + j] = v[j] * inv;
  }
  __syncthreads();

  // descriptor build: 32 q x 128 (m,j) = 4096, 16 per thread, coalesced
#pragma unroll
  for (int i = 0; i < 16; ++i) {
    const int e = i * 256 + t;
    const int q = e >> 7, rem = e & 127;
    const int m = rem >> 4, j = rem & 15, l = j >> 2;
    const int jo = m * 16 + j;
    const float ox = offs[q * 256 + 2 * jo], oy = offs[q * 256 + 2 * jo + 1];
    const float aw = attw[q * 128 + jo];
    const float rx = refs[q * 8 + l * 2 + 0], ry = refs[q * 8 + l * 2 + 1];
    const int W = 128 >> l;
    const float x = rx * (float)W + ox - 0.5f;
    const float y = ry * (float)W + oy - 0.5f;
    const float xc = fminf(fmaxf(x, -8.f), 503.f);
    const float yc = fminf(fmaxf(y, -8.f), 503.f);
    const uint32_t xfix = (uint32_t)((xc + 8.f) * 128.f + 0.5f);
    const uint32_t yfix = (uint32_t)((yc + 8.f) * 128.f + 0.5f);
    uint2 dsc;
    dsc.x = xfix | (yfix << 16);
    dsc.y = (uint32_t)__half_as_ushort(__float2half_rn(aw));
    descD[((size_t)(n * 8 + m) * QCHc + q0c + q) * 16 + j] = dsc;
  }
}

// ---------------------------------------------------------------------------
// Kernel: cross-group pipelined gather (R17, VGPR=64) at LB(256,4).
// ---------------------------------------------------------------------------
__global__ __launch_bounds__(256, 4) void k_gather(
    const uint2* __restrict__ descD, const __half* __restrict__ value,
    short* __restrict__ accB, int qbase) {
  const int t = threadIdx.x;
  const int d4 = t & 3, ql = t >> 2;          // 64 queries per block
  const int bid = blockIdx.x;
  const int s = bid & 15, qc = bid >> 4;      // slice, query-chunk (170)
  const int n = s >> 3, m = s & 7;
  const int q = qc * 64 + ql;                 // within chunk
  const uint4* dp4 = (const uint4*)(descD + ((size_t)(n * 8 + m) * QCHc + q) * 16);
  const char* vb = (const char*)value +
                   (size_t)((n * 8 + m) * LEN) * 64 + d4 * 16;

  uint4 dd[8];
#pragma unroll
  for (int i = 0; i < 8; ++i) dd[i] = dp4[i];
  __builtin_amdgcn_sched_barrier(0);

  float accf[8];
#pragma unroll
  for (int i = 0; i < 8; ++i) accf[i] = 0.f;

  union V { uint4 v; __half2 h[4]; };
  V rA[8], rB[8];
  __half2 hwA[8], hwB[8];

#define DECJ(G, ODD, R, HW, BASE)                                             \
  {                                                                           \
    constexpr int l_ = (G) >> 1;                                              \
    constexpr int W_ = 128 >> l_;                                             \
    constexpr int stl_ = (l_ == 0) ? 0 : (l_ == 1) ? 16384 : (l_ == 2) ? 20480 : 21504; \
    const uint32_t lo_ = (ODD) ? dd[G].z : dd[G].x;                           \
    const uint32_t hi_ = (ODD) ? dd[G].w : dd[G].y;                           \
    const int xf_ = (int)(lo_ & 0xffffu), yf_ = (int)(lo_ >> 16);             \
    const float aw_ = __half2float(__ushort_as_half((unsigned short)(hi_ & 0xffffu))); \
    const int xi_ = (xf_ >> 7) - 8, yi_ = (yf_ >> 7) - 8;                     \
    const float fx_ = (float)(xf_ & 127) * 0.0078125f;                        \
    const float fy_ = (float)(yf_ & 127) * 0.0078125f;                        \
    float wx0_ = 1.f - fx_, wx1_ = fx_, wy0_ = 1.f - fy_, wy1_ = fy_;         \
    if (xi_ < 0 || xi_ >= W_)         wx0_ = 0.f;                             \
    if (xi_ + 1 < 0 || xi_ + 1 >= W_) wx1_ = 0.f;                             \
    if (yi_ < 0 || yi_ >= W_)         wy0_ = 0.f;                             \
    if (yi_ + 1 < 0 || yi_ + 1 >= W_) wy1_ = 0.f;                             \
    const int x0_ = min(max(xi_, 0), W_ - 1), x1_ = min(max(xi_ + 1, 0), W_ - 1); \
    const int y0_ = min(max(yi_, 0), W_ - 1), y1_ = min(max(yi_ + 1, 0), W_ - 1); \
    HW[(BASE) + 0] = __float2half2_rn(wx0_ * wy0_ * aw_);                     \
    HW[(BASE) + 1] = __float2half2_rn(wx1_ * wy0_ * aw_);                     \
    HW[(BASE) + 2] = __float2half2_rn(wx0_ * wy1_ * aw_);                     \
    HW[(BASE) + 3] = __float2half2_rn(wx1_ * wy1_ * aw_);                     \
    R[(BASE) + 0].v = *(const uint4*)(vb + (size_t)(stl_ + y0_ * W_ + x0_) * 64u); \
    R[(BASE) + 1].v = *(const uint4*)(vb + (size_t)(stl_ + y0_ * W_ + x1_) * 64u); \
    R[(BASE) + 2].v = *(const uint4*)(vb + (size_t)(stl_ + y1_ * W_ + x0_) * 64u); \
    R[(BASE) + 3].v = *(const uint4*)(vb + (size_t)(stl_ + y1_ * W_ + x1_) * 64u); \
  }

#define DECG(G, R, HW)                                                        \
  DECJ(G, 0, R, HW, 0)                                                        \
  DECJ(G, 1, R, HW, 4)                                                        \
  __builtin_amdgcn_sched_barrier(0);

#define CONSG(R, HW)                                                          \
  {                                                                           \
    __half2 acch[4];                                                          \
    _Pragma("unroll") for (int i_ = 0; i_ < 4; ++i_)                          \
        acch[i_] = __float2half2_rn(0.f);                                     \
    _Pragma("unroll") for (int c_ = 0; c_ < 8; ++c_) {                        \
      _Pragma("unroll") for (int i_ = 0; i_ < 4; ++i_)                        \
          acch[i_] = __hfma2(R[c_].h[i_], HW[c_], acch[i_]);                  \
    }                                                                         \
    _Pragma("unroll") for (int i_ = 0; i_ < 4; ++i_) {                        \
      const float2 f_ = __half22float2(acch[i_]);                             \
      accf[2 * i_] += f_.x; accf[2 * i_ + 1] += f_.y;                         \
    }                                                                         \
  }

  DECG(0, rA, hwA)
  DECG(1, rB, hwB)
  CONSG(rA, hwA)
  DECG(2, rA, hwA)
  CONSG(rB, hwB)
  DECG(3, rB, hwB)
  CONSG(rA, hwA)
  DECG(4, rA, hwA)
  CONSG(rB, hwB)
  DECG(5, rB, hwB)
  CONSG(rA, hwA)
  DECG(6, rA, hwA)
  CONSG(rB, hwB)
  DECG(7, rB, hwB)
  CONSG(rA, hwA)
  CONSG(rB, hwB)
#undef DECJ
#undef DECG
#undef CONSG

  short8v o;
#pragma unroll
  for (int i = 0; i < 8; ++i) o[i] = f2bf(accf[i]);
  *(short8v*)(accB + ((size_t)n * LEN + qbase + q) * 256 + m * 32 + d4 * 8) = o;
}

// ---------------------------------------------------------------------------
extern "C" void kernel_launch(void* const* d_in, const int* in_sizes, int n_in,
                              void* d_out, int out_size, void* d_ws, size_t ws_size,
                              hipStream_t stream) {
  const float* query = (const float*)d_in[0];
  const float* refp  = (const float*)d_in[1];
  const float* infl  = (const float*)d_in[2];
  const float* Woff  = (const float*)d_in[3];
  const float* boff  = (const float*)d_in[4];
  const float* Wattn = (const float*)d_in[5];
  const float* battn = (const float*)d_in[6];
  const float* Wval  = (const float*)d_in[7];
  const float* bval  = (const float*)d_in[8];
  const float* Wout  = (const float*)d_in[9];
  const float* bout  = (const float*)d_in[10];
  float* out = (float*)d_out;

  char* ws = (char*)d_ws;
  __half* value = (__half*)ws;                   // 22,282,240 B
  short*  accB  = (short*)(ws + 22282240);       // 22,282,240 B
  uint2*  desc8 = (uint2*)(ws + 44564480);       // 22,282,240 B (one chunk)
  short*  WvP   = (short*)(ws + 66846720);       // 131,072 B
  short*  WdP   = (short*)(ws + 66977792);       // 196,608 B
  short*  WoP   = (short*)(ws + 67174400);       // 131,072 B  (total 67.3 MB)

  k_wpack<<<dim3(384, 3), 256, 0, stream>>>(Wval, Woff, Wattn, Wout,
                                            WvP, WdP, WoP);

  k_valproj<<<(NB * LEN) / 32, 256, 0, stream>>>(infl, WvP, bval, value);

  for (int c = 0; c < 2; ++c) {
    k_desc<<<NB * (QCHc / 32), 256, 0, stream>>>(query, refp, WdP, boff, battn,
                                                 desc8, c * QCHc);
    k_gather<<<16 * (QCHc / 64), 256, 0, stream>>>(desc8, value, accB, c * QCHc);
  }

  k_outproj<<<(NB * LEN) / 32, 256, 0, stream>>>(accB, WoP, bout, out);
}

// Round 20
// 154.530 us; speedup vs baseline: 2.1236x; 1.0144x over previous
//
#include <hip/hip_runtime.h>
#include <hip/hip_fp16.h>
#include <math.h>
#include <stdint.h>

// MSDeformAttn. N=2, C=256, M=8, L=4, P=4, D=32, LEN=21760
// R20: zero-padded value levels (W+2 x H+2) -> gather DECJ has no border
//      compares/clamps (~50 -> ~25 VALU/j). Clamp-to-[-1,W] in desc makes
//      zero-padding semantics exact. Pipeline/fence structure = R17/R19.
// Padded geometry: starts {0,16900,21256,22412}, widths {130,66,34,18},
// PADPIX = 22736 pixels/slice.

constexpr int NB  = 2;
constexpr int C   = 256;
constexpr int M   = 8;
constexpr int D   = 32;
constexpr int LEN = 21760;
constexpr int QCHc = LEN / 2;     // 10880 queries per chunk (per batch)
constexpr int PADPIX = 22736;

typedef __attribute__((ext_vector_type(8))) short short8v;
typedef __attribute__((ext_vector_type(4))) float f32x4;

__device__ __forceinline__ short f2bf(float x) {
  uint32_t u = __float_as_uint(x);
  u = (u + 0x7fffu + ((u >> 16) & 1u)) >> 16;
  return (short)u;
}

// ---------------------------------------------------------------------------
// Weight prepack into per-fragment-coalesced layout (proven R10)
// ---------------------------------------------------------------------------
__global__ __launch_bounds__(256) void k_wpack(
    const float* __restrict__ Wval, const float* __restrict__ Woff,
    const float* __restrict__ Wattn, const float* __restrict__ Wout,
    short* __restrict__ WvP, short* __restrict__ WdP, short* __restrict__ WoP) {
  const int job = blockIdx.y;
  const int ncols = (job == 1) ? 384 : 256;
  const int NCG = ncols / 16;
  const int elems = 256 * ncols;
  const int idx = blockIdx.x * 256 + threadIdx.x;
  if (idx >= elems) return;
  const int e    = idx & 7;
  const int lane = (idx >> 3) & 63;
  const int lr = lane & 15, lk = lane >> 4;
  const int cgks = idx >> 9;
  const int cg = cgks % NCG, ks = cgks / NCG;
  const int k = ks * 32 + lk * 8 + e;
  const int col = cg * 16 + lr;
  float v;
  if (job == 0)      v = Wval[(size_t)k * 256 + col];
  else if (job == 2) v = Wout[(size_t)k * 256 + col];
  else               v = (col < 256) ? Woff[(size_t)k * 256 + col]
                                     : Wattn[(size_t)k * 128 + col - 256];
  short* dst = (job == 0) ? WvP : (job == 1) ? WdP : WoP;
  dst[idx] = f2bf(v);
}

// ---------------------------------------------------------------------------
// Zero the 1-px padding ring of every level of every slice (1 MB total).
// grid = (16 slices, 4 levels)
// ---------------------------------------------------------------------------
__global__ __launch_bounds__(256) void k_zpad(__half* __restrict__ value) {
  const int s = blockIdx.x, l = blockIdx.y;
  const int Wp  = (l == 0) ? 130 : (l == 1) ? 66 : (l == 2) ? 34 : 18;
  const int stp = (l == 0) ? 0 : (l == 1) ? 16900 : (l == 2) ? 21256 : 22412;
  const int cells = 4 * Wp - 4;
  const uint4 z = {0u, 0u, 0u, 0u};
  char* base = (char*)value + (size_t)s * PADPIX * 64;
  for (int i = threadIdx.x; i < cells * 4; i += 256) {
    const int cell = i >> 2, d4 = i & 3;
    int row, col;
    if (cell < Wp)            { row = 0;       col = cell; }
    else if (cell < 2 * Wp)   { row = Wp - 1;  col = cell - Wp; }
    else { const int c2 = cell - 2 * Wp; row = 1 + (c2 >> 1); col = (c2 & 1) ? (Wp - 1) : 0; }
    *(uint4*)(base + (size_t)(stp + row * Wp + col) * 64 + d4 * 16) = z;
  }
}

__device__ __forceinline__ short8v ldBP(const short* __restrict__ WP, int NCG,
                                        int cg, int ks, int lane) {
  const int4 v = *(const int4*)(WP + ((size_t)((ks * NCG + cg) * 64 + lane)) * 8);
  union { int4 i; short8v s; } u; u.i = v; return u.s;
}

// ---------------------------------------------------------------------------
// LDS staging (32 rows x 256 k, bf16, XOR-swizzled) + A fragment loads
// ---------------------------------------------------------------------------
__device__ __forceinline__ void stage_cast(const float* __restrict__ p, char* sm, int t) {
  const int r = t >> 3, seg = t & 7;
  const float4* s = (const float4*)(p + (size_t)r * C + seg * 32);
  short v[32];
#pragma unroll
  for (int i = 0; i < 8; ++i) {
    float4 f = s[i];
    v[i * 4 + 0] = f2bf(f.x); v[i * 4 + 1] = f2bf(f.y);
    v[i * 4 + 2] = f2bf(f.z); v[i * 4 + 3] = f2bf(f.w);
  }
#pragma unroll
  for (int i = 0; i < 4; ++i) {
    const int kb = (seg * 32 + i * 8) * 2;
    *(int4*)(sm + r * 512 + (kb ^ ((r & 7) << 4))) = ((const int4*)v)[i];
  }
}

__device__ __forceinline__ void stage_bf16(const short* __restrict__ p, char* sm, int t) {
  const int r = t >> 3, seg = t & 7;
  const int4* s = (const int4*)(p + (size_t)r * C + seg * 32);
#pragma unroll
  for (int i = 0; i < 4; ++i) {
    const int kb = (seg * 32 + i * 8) * 2;
    *(int4*)(sm + r * 512 + (kb ^ ((r & 7) << 4))) = s[i];
  }
}

__device__ __forceinline__ short8v ldsA(const char* sm, int lane, int rt, int ks) {
  const int row = rt * 16 + (lane & 15);
  const int kb  = ks * 64 + ((lane >> 4) << 4);
  const int4 v = *(const int4*)(sm + row * 512 + (kb ^ ((row & 7) << 4)));
  union { int4 i; short8v s; } u; u.i = v; return u.s;
}

#define MFMA __builtin_amdgcn_mfma_f32_16x16x32_bf16

// ---------------------------------------------------------------------------
// GEMM body shared by valproj/outproj (proven in R10)
// ---------------------------------------------------------------------------
#define GEMM_BODY(WP)                                                       \
  short8v a[2][8];                                                          \
  _Pragma("unroll") for (int rt = 0; rt < 2; ++rt)                          \
  _Pragma("unroll") for (int ks = 0; ks < 8; ++ks)                          \
      a[rt][ks] = ldsA(smA, lane, rt, ks);                                  \
  f32x4 acc[2][4];                                                          \
  _Pragma("unroll") for (int rt = 0; rt < 2; ++rt)                          \
  _Pragma("unroll") for (int ct = 0; ct < 4; ++ct)                          \
      acc[rt][ct] = (f32x4){0.f, 0.f, 0.f, 0.f};                            \
  short8v b0[8], b1[8];                                                     \
  _Pragma("unroll") for (int ks = 0; ks < 8; ++ks)                          \
      b0[ks] = ldBP(WP, 16, cg0 + 0, ks, lane);                             \
  _Pragma("unroll") for (int ks = 0; ks < 8; ++ks)                          \
      b1[ks] = ldBP(WP, 16, cg0 + 1, ks, lane);                             \
  _Pragma("unroll") for (int ks = 0; ks < 8; ++ks) {                        \
    acc[0][0] = MFMA(a[0][ks], b0[ks], acc[0][0], 0, 0, 0);                 \
    acc[1][0] = MFMA(a[1][ks], b0[ks], acc[1][0], 0, 0, 0);                 \
  }                                                                         \
  _Pragma("unroll") for (int ks = 0; ks < 8; ++ks)                          \
      b0[ks] = ldBP(WP, 16, cg0 + 2, ks, lane);                             \
  _Pragma("unroll") for (int ks = 0; ks < 8; ++ks) {                        \
    acc[0][1] = MFMA(a[0][ks], b1[ks], acc[0][1], 0, 0, 0);                 \
    acc[1][1] = MFMA(a[1][ks], b1[ks], acc[1][1], 0, 0, 0);                 \
  }                                                                         \
  _Pragma("unroll") for (int ks = 0; ks < 8; ++ks)                          \
      b1[ks] = ldBP(WP, 16, cg0 + 3, ks, lane);                             \
  _Pragma("unroll") for (int ks = 0; ks < 8; ++ks) {                        \
    acc[0][2] = MFMA(a[0][ks], b0[ks], acc[0][2], 0, 0, 0);                 \
    acc[1][2] = MFMA(a[1][ks], b0[ks], acc[1][2], 0, 0, 0);                 \
  }                                                                         \
  _Pragma("unroll") for (int ks = 0; ks < 8; ++ks) {                        \
    acc[0][3] = MFMA(a[0][ks], b1[ks], acc[0][3], 0, 0, 0);                 \
    acc[1][3] = MFMA(a[1][ks], b1[ks], acc[1][3], 0, 0, 0);                 \
  }

// ---------------------------------------------------------------------------
// Kernel: value = bf16mm(input_flatten, WvP) + bv -> fp16 value[slice][padpix][d]
// ---------------------------------------------------------------------------
__global__ __launch_bounds__(256, 2) void k_valproj(
    const float* __restrict__ infl, const short* __restrict__ WvP,
    const float* __restrict__ bv, __half* __restrict__ value) {
  __shared__ __align__(16) char smA[16384];
  const int t = threadIdx.x, lane = t & 63, w = t >> 6;
  const int r0 = blockIdx.x * 32;
  stage_cast(infl + (size_t)r0 * C, smA, t);
  __syncthreads();
  const int cg0 = w * 4;
  const int lr = lane & 15, lk = lane >> 4;
  GEMM_BODY(WvP)

  const int n = (blockIdx.x >= (LEN / 32)) ? 1 : 0;
  const int pixbase = r0 - n * LEN;

  // padded pixel indices for this thread's 8 row-slots (shared across ct)
  int pidx8[2][4];
#pragma unroll
  for (int rt = 0; rt < 2; ++rt)
#pragma unroll
    for (int r = 0; r < 4; ++r) {
      const int pix = pixbase + rt * 16 + lk * 4 + r;
      int pi;
      if (pix < 16384)      { const int y = pix >> 7;           pi = (y + 1) * 130 + (pix & 127) + 1; }
      else if (pix < 20480) { const int y = (pix - 16384) >> 6; pi = 16900 + (y + 1) * 66 + (pix & 63) + 1; }
      else if (pix < 21504) { const int y = (pix - 20480) >> 5; pi = 21256 + (y + 1) * 34 + (pix & 31) + 1; }
      else                  { const int y = (pix - 21504) >> 4; pi = 22412 + (y + 1) * 18 + (pix & 15) + 1; }
      pidx8[rt][r] = pi;
    }

#pragma unroll
  for (int ct = 0; ct < 4; ++ct) {
    const int col = (cg0 + ct) * 16 + lr;
    const float bb = bv[col];
    const int m = col >> 5, d = col & 31;
    __half* vp = value + ((size_t)(n * 8 + m) * PADPIX) * 32 + d;
#pragma unroll
    for (int rt = 0; rt < 2; ++rt)
#pragma unroll
      for (int r = 0; r < 4; ++r)
        vp[(size_t)pidx8[rt][r] * 32] = __float2half(acc[rt][ct][r] + bb);
  }
}

// ---------------------------------------------------------------------------
// Kernel: out = bf16mm(accB, WoP) + bo (fp32 out)
// ---------------------------------------------------------------------------
__global__ __launch_bounds__(256, 2) void k_outproj(
    const short* __restrict__ accB, const short* __restrict__ WoP,
    const float* __restrict__ bo, float* __restrict__ out) {
  __shared__ __align__(16) char smA[16384];
  const int t = threadIdx.x, lane = t & 63, w = t >> 6;
  const int r0 = blockIdx.x * 32;
  stage_bf16(accB + (size_t)r0 * C, smA, t);
  __syncthreads();
  const int cg0 = w * 4;
  const int lr = lane & 15, lk = lane >> 4;
  GEMM_BODY(WoP)

#pragma unroll
  for (int ct = 0; ct < 4; ++ct) {
    const int col = (cg0 + ct) * 16 + lr;
    const float bb = bo[col];
#pragma unroll
    for (int rt = 0; rt < 2; ++rt)
#pragma unroll
      for (int r = 0; r < 4; ++r) {
        const int row = r0 + rt * 16 + lk * 4 + r;
        out[(size_t)row * C + col] = acc[rt][ct][r] + bb;
      }
  }
}

// ---------------------------------------------------------------------------
// Kernel: offsets/attn GEMM + softmax + 8B fixed-point descriptor build
// descD[((n*8+m)*QCHc + q)*16 + j] : uint2 {xfix|(yfix<<16), aw_half}
// fixed point: (coord + 1) * 128 with coord clamped to [-1, W] (per level).
// Clamp + zero-padded value buffer make padding_mode='zeros' exact.
// ---------------------------------------------------------------------------
__global__ __launch_bounds__(256, 3) void k_desc(
    const float* __restrict__ query, const float* __restrict__ refp,
    const short* __restrict__ WdP, const float* __restrict__ boff,
    const float* __restrict__ battn, uint2* __restrict__ descD, int qbase) {
  __shared__ __align__(16) char smem[50176];
  char*  smA  = smem;                       // [32][512] bf16 A-tile
  float* offs = (float*)smem;               // [32][256] (aliases smA; used later)
  float* attw = (float*)(smem + 32768);     // [32][128]
  float* refs = (float*)(smem + 49152);     // [32][8]

  const int t = threadIdx.x, lane = t & 63, w = t >> 6;
  const int n   = blockIdx.x / 340;
  const int q0c = (blockIdx.x % 340) * 32;
  const size_t qrow = (size_t)n * LEN + qbase + q0c;

  refs[t] = refp[qrow * 8 + t];
  stage_cast(query + qrow * C, smA, t);
  __syncthreads();

  f32x4 acc[2][6];
#pragma unroll
  for (int a = 0; a < 2; ++a)
#pragma unroll
    for (int b = 0; b < 6; ++b) acc[a][b] = (f32x4){0.f, 0.f, 0.f, 0.f};
  const int cgb = w * 6;
#pragma unroll
  for (int ks = 0; ks < 8; ++ks) {
    const short8v a0 = ldsA(smA, lane, 0, ks);
    const short8v a1 = ldsA(smA, lane, 1, ks);
#pragma unroll
    for (int ct = 0; ct < 6; ++ct) {
      const short8v b = ldBP(WdP, 24, cgb + ct, ks, lane);
      acc[0][ct] = MFMA(a0, b, acc[0][ct], 0, 0, 0);
      acc[1][ct] = MFMA(a1, b, acc[1][ct], 0, 0, 0);
    }
  }
  __syncthreads();   // all LDS A reads complete before aliasing writes

#pragma unroll
  for (int ct = 0; ct < 6; ++ct) {
    const int col = (cgb + ct) * 16 + (lane & 15);
    const float bb = (col < 256) ? boff[col] : battn[col - 256];
#pragma unroll
    for (int rt = 0; rt < 2; ++rt)
#pragma unroll
      for (int r = 0; r < 4; ++r) {
        const int row = rt * 16 + ((lane >> 4) << 2) + r;
        const float vv = acc[rt][ct][r] + bb;
        if (col < 256) offs[row * 256 + col] = vv;
        else           attw[row * 128 + col - 256] = vv;
      }
  }
  __syncthreads();

  // softmax over 16 per (q, m): 256 tasks
  {
    const int q = t >> 3, m = t & 7;
    float v[16], mx = -1e30f;
#pragma unroll
    for (int j = 0; j < 16; ++j) { v[j] = attw[q * 128 + m * 16 + j]; mx = fmaxf(mx, v[j]); }
    float s = 0.f;
#pragma unroll
    for (int j = 0; j < 16; ++j) { v[j] = __expf(v[j] - mx); s += v[j]; }
    const float inv = 1.f / s;
#pragma unroll
    for (int j = 0; j < 16; ++j) attw[q * 128 + m * 16 + j] = v[j] * inv;
  }
  __syncthreads();

  // descriptor build: 32 q x 128 (m,j) = 4096, 16 per thread, coalesced
#pragma unroll
  for (int i = 0; i < 16; ++i) {
    const int e = i * 256 + t;
    const int q = e >> 7, rem = e & 127;
    const int m = rem >> 4, j = rem & 15, l = j >> 2;
    const int jo = m * 16 + j;
    const float ox = offs[q * 256 + 2 * jo], oy = offs[q * 256 + 2 * jo + 1];
    const float aw = attw[q * 128 + jo];
    const float rx = refs[q * 8 + l * 2 + 0], ry = refs[q * 8 + l * 2 + 1];
    const int W = 128 >> l;
    const float fW = (float)W;
    const float x = rx * fW + ox - 0.5f;
    const float y = ry * fW + oy - 0.5f;
    const float xc = fminf(fmaxf(x, -1.f), fW);
    const float yc = fminf(fmaxf(y, -1.f), fW);
    const uint32_t xfix = (uint32_t)((xc + 1.f) * 128.f + 0.5f);
    const uint32_t yfix = (uint32_t)((yc + 1.f) * 128.f + 0.5f);
    uint2 dsc;
    dsc.x = xfix | (yfix << 16);
    dsc.y = (uint32_t)__half_as_ushort(__float2half_rn(aw));
    descD[((size_t)(n * 8 + m) * QCHc + q0c + q) * 16 + j] = dsc;
  }
}

// ---------------------------------------------------------------------------
// Kernel: cross-group pipelined gather over PADDED levels — no border logic.
// ---------------------------------------------------------------------------
__global__ __launch_bounds__(256, 4) void k_gather(
    const uint2* __restrict__ descD, const __half* __restrict__ value,
    short* __restrict__ accB, int qbase) {
  const int t = threadIdx.x;
  const int d4 = t & 3, ql = t >> 2;          // 64 queries per block
  const int bid = blockIdx.x;
  const int s = bid & 15, qc = bid >> 4;      // slice, query-chunk (170)
  const int n = s >> 3, m = s & 7;
  const int q = qc * 64 + ql;                 // within chunk
  const uint4* dp4 = (const uint4*)(descD + ((size_t)(n * 8 + m) * QCHc + q) * 16);
  const char* vb = (const char*)value +
                   (size_t)((n * 8 + m)) * PADPIX * 64 + d4 * 16;

  uint4 dd[8];
#pragma unroll
  for (int i = 0; i < 8; ++i) dd[i] = dp4[i];
  __builtin_amdgcn_sched_barrier(0);

  float accf[8];
#pragma unroll
  for (int i = 0; i < 8; ++i) accf[i] = 0.f;

  union V { uint4 v; __half2 h[4]; };
  V rA[8], rB[8];
  __half2 hwA[8], hwB[8];

#define DECJ(G, ODD, R, HW, BASE)                                             \
  {                                                                           \
    constexpr int l_ = (G) >> 1;                                              \
    constexpr int W_ = 128 >> l_;                                             \
    constexpr int Wp_ = W_ + 2;                                               \
    constexpr int stp_ = (l_ == 0) ? 0 : (l_ == 1) ? 16900 : (l_ == 2) ? 21256 : 22412; \
    const uint32_t lo_ = (ODD) ? dd[G].z : dd[G].x;                           \
    const uint32_t hi_ = (ODD) ? dd[G].w : dd[G].y;                           \
    const int xf_ = (int)(lo_ & 0xffffu), yf_ = (int)(lo_ >> 16);             \
    const float aw_ = __half2float(__ushort_as_half((unsigned short)(hi_ & 0xffffu))); \
    const int xi_ = xf_ >> 7, yi_ = yf_ >> 7;                                 \
    const float fx_ = (float)(xf_ & 127) * 0.0078125f;                        \
    const float fy_ = (float)(yf_ & 127) * 0.0078125f;                        \
    const float wx0_ = 1.f - fx_;                                             \
    const float wy0a_ = (1.f - fy_) * aw_;                                    \
    const float wy1a_ = fy_ * aw_;                                            \
    HW[(BASE) + 0] = __float2half2_rn(wx0_ * wy0a_);                          \
    HW[(BASE) + 1] = __float2half2_rn(fx_ * wy0a_);                           \
    HW[(BASE) + 2] = __float2half2_rn(wx0_ * wy1a_);                          \
    HW[(BASE) + 3] = __float2half2_rn(fx_ * wy1a_);                           \
    const char* a0_ = vb + (size_t)(stp_ + yi_ * Wp_ + xi_) * 64u;            \
    const char* a1_ = a0_ + Wp_ * 64;                                         \
    R[(BASE) + 0].v = *(const uint4*)(a0_);                                   \
    R[(BASE) + 1].v = *(const uint4*)(a0_ + 64);                              \
    R[(BASE) + 2].v = *(const uint4*)(a1_);                                   \
    R[(BASE) + 3].v = *(const uint4*)(a1_ + 64);                              \
  }

#define DECG(G, R, HW)                                                        \
  DECJ(G, 0, R, HW, 0)                                                        \
  DECJ(G, 1, R, HW, 4)                                                        \
  __builtin_amdgcn_sched_barrier(0);

#define CONSG(R, HW)                                                          \
  {                                                                           \
    __half2 acch[4];                                                          \
    _Pragma("unroll") for (int i_ = 0; i_ < 4; ++i_)                          \
        acch[i_] = __float2half2_rn(0.f);                                     \
    _Pragma("unroll") for (int c_ = 0; c_ < 8; ++c_) {                        \
      _Pragma("unroll") for (int i_ = 0; i_ < 4; ++i_)                        \
          acch[i_] = __hfma2(R[c_].h[i_], HW[c_], acch[i_]);                  \
    }                                                                         \
    _Pragma("unroll") for (int i_ = 0; i_ < 4; ++i_) {                        \
      const float2 f_ = __half22float2(acch[i_]);                             \
      accf[2 * i_] += f_.x; accf[2 * i_ + 1] += f_.y;                         \
    }                                                                         \
  }

  DECG(0, rA, hwA)
  DECG(1, rB, hwB)
  CONSG(rA, hwA)
  DECG(2, rA, hwA)
  CONSG(rB, hwB)
  DECG(3, rB, hwB)
  CONSG(rA, hwA)
  DECG(4, rA, hwA)
  CONSG(rB, hwB)
  DECG(5, rB, hwB)
  CONSG(rA, hwA)
  DECG(6, rA, hwA)
  CONSG(rB, hwB)
  DECG(7, rB, hwB)
  CONSG(rA, hwA)
  CONSG(rB, hwB)
#undef DECJ
#undef DECG
#undef CONSG

  short8v o;
#pragma unroll
  for (int i = 0; i < 8; ++i) o[i] = f2bf(accf[i]);
  *(short8v*)(accB + ((size_t)n * LEN + qbase + q) * 256 + m * 32 + d4 * 8) = o;
}

// ---------------------------------------------------------------------------
extern "C" void kernel_launch(void* const* d_in, const int* in_sizes, int n_in,
                              void* d_out, int out_size, void* d_ws, size_t ws_size,
                              hipStream_t stream) {
  const float* query = (const float*)d_in[0];
  const float* refp  = (const float*)d_in[1];
  const float* infl  = (const float*)d_in[2];
  const float* Woff  = (const float*)d_in[3];
  const float* boff  = (const float*)d_in[4];
  const float* Wattn = (const float*)d_in[5];
  const float* battn = (const float*)d_in[6];
  const float* Wval  = (const float*)d_in[7];
  const float* bval  = (const float*)d_in[8];
  const float* Wout  = (const float*)d_in[9];
  const float* bout  = (const float*)d_in[10];
  float* out = (float*)d_out;

  char* ws = (char*)d_ws;
  __half* value = (__half*)ws;                   // 16*22736*64 = 23,281,664 B
  short*  accB  = (short*)(ws + 23281664);       // 22,282,240 B
  uint2*  desc8 = (uint2*)(ws + 45563904);       // 22,282,240 B (one chunk)
  short*  WvP   = (short*)(ws + 67846144);       // 131,072 B
  short*  WdP   = (short*)(ws + 67977216);       // 196,608 B
  short*  WoP   = (short*)(ws + 68173824);       // 131,072 B  (total 68.3 MB)

  k_wpack<<<dim3(384, 3), 256, 0, stream>>>(Wval, Woff, Wattn, Wout,
                                            WvP, WdP, WoP);
  k_zpad<<<dim3(16, 4), 256, 0, stream>>>(value);

  k_valproj<<<(NB * LEN) / 32, 256, 0, stream>>>(infl, WvP, bval, value);

  for (int c = 0; c < 2; ++c) {
    k_desc<<<NB * (QCHc / 32), 256, 0, stream>>>(query, refp, WdP, boff, battn,
                                                 desc8, c * QCHc);
    k_gather<<<16 * (QCHc / 64), 256, 0, stream>>>(desc8, value, accB, c * QCHc);
  }

  k_outproj<<<(NB * LEN) / 32, 256, 0, stream>>>(accB, WoP, bout, out);
}

// Round 21
// 148.467 us; speedup vs baseline: 2.2103x; 1.0408x over previous
//
#include <hip/hip_runtime.h>
#include <hip/hip_fp16.h>
#include <math.h>
#include <stdint.h>

// MSDeformAttn. N=2, C=256, M=8, L=4, P=4, D=32, LEN=21760
// R21: R20 with single full-LEN chunk (desc buffer 44.6MB fits in ws):
//      1 desc + 1 gather launch instead of 2+2; kernels unchanged.

constexpr int NB  = 2;
constexpr int C   = 256;
constexpr int M   = 8;
constexpr int D   = 32;
constexpr int LEN = 21760;
constexpr int PADPIX = 22736;

typedef __attribute__((ext_vector_type(8))) short short8v;
typedef __attribute__((ext_vector_type(4))) float f32x4;

__device__ __forceinline__ short f2bf(float x) {
  uint32_t u = __float_as_uint(x);
  u = (u + 0x7fffu + ((u >> 16) & 1u)) >> 16;
  return (short)u;
}

// ---------------------------------------------------------------------------
// Weight prepack into per-fragment-coalesced layout (proven R10)
// ---------------------------------------------------------------------------
__global__ __launch_bounds__(256) void k_wpack(
    const float* __restrict__ Wval, const float* __restrict__ Woff,
    const float* __restrict__ Wattn, const float* __restrict__ Wout,
    short* __restrict__ WvP, short* __restrict__ WdP, short* __restrict__ WoP) {
  const int job = blockIdx.y;
  const int ncols = (job == 1) ? 384 : 256;
  const int NCG = ncols / 16;
  const int elems = 256 * ncols;
  const int idx = blockIdx.x * 256 + threadIdx.x;
  if (idx >= elems) return;
  const int e    = idx & 7;
  const int lane = (idx >> 3) & 63;
  const int lr = lane & 15, lk = lane >> 4;
  const int cgks = idx >> 9;
  const int cg = cgks % NCG, ks = cgks / NCG;
  const int k = ks * 32 + lk * 8 + e;
  const int col = cg * 16 + lr;
  float v;
  if (job == 0)      v = Wval[(size_t)k * 256 + col];
  else if (job == 2) v = Wout[(size_t)k * 256 + col];
  else               v = (col < 256) ? Woff[(size_t)k * 256 + col]
                                     : Wattn[(size_t)k * 128 + col - 256];
  short* dst = (job == 0) ? WvP : (job == 1) ? WdP : WoP;
  dst[idx] = f2bf(v);
}

// ---------------------------------------------------------------------------
// Zero the 1-px padding ring of every level of every slice (1 MB total).
// ---------------------------------------------------------------------------
__global__ __launch_bounds__(256) void k_zpad(__half* __restrict__ value) {
  const int s = blockIdx.x, l = blockIdx.y;
  const int Wp  = (l == 0) ? 130 : (l == 1) ? 66 : (l == 2) ? 34 : 18;
  const int stp = (l == 0) ? 0 : (l == 1) ? 16900 : (l == 2) ? 21256 : 22412;
  const int cells = 4 * Wp - 4;
  const uint4 z = {0u, 0u, 0u, 0u};
  char* base = (char*)value + (size_t)s * PADPIX * 64;
  for (int i = threadIdx.x; i < cells * 4; i += 256) {
    const int cell = i >> 2, d4 = i & 3;
    int row, col;
    if (cell < Wp)            { row = 0;       col = cell; }
    else if (cell < 2 * Wp)   { row = Wp - 1;  col = cell - Wp; }
    else { const int c2 = cell - 2 * Wp; row = 1 + (c2 >> 1); col = (c2 & 1) ? (Wp - 1) : 0; }
    *(uint4*)(base + (size_t)(stp + row * Wp + col) * 64 + d4 * 16) = z;
  }
}

__device__ __forceinline__ short8v ldBP(const short* __restrict__ WP, int NCG,
                                        int cg, int ks, int lane) {
  const int4 v = *(const int4*)(WP + ((size_t)((ks * NCG + cg) * 64 + lane)) * 8);
  union { int4 i; short8v s; } u; u.i = v; return u.s;
}

// ---------------------------------------------------------------------------
// LDS staging (32 rows x 256 k, bf16, XOR-swizzled) + A fragment loads
// ---------------------------------------------------------------------------
__device__ __forceinline__ void stage_cast(const float* __restrict__ p, char* sm, int t) {
  const int r = t >> 3, seg = t & 7;
  const float4* s = (const float4*)(p + (size_t)r * C + seg * 32);
  short v[32];
#pragma unroll
  for (int i = 0; i < 8; ++i) {
    float4 f = s[i];
    v[i * 4 + 0] = f2bf(f.x); v[i * 4 + 1] = f2bf(f.y);
    v[i * 4 + 2] = f2bf(f.z); v[i * 4 + 3] = f2bf(f.w);
  }
#pragma unroll
  for (int i = 0; i < 4; ++i) {
    const int kb = (seg * 32 + i * 8) * 2;
    *(int4*)(sm + r * 512 + (kb ^ ((r & 7) << 4))) = ((const int4*)v)[i];
  }
}

__device__ __forceinline__ void stage_bf16(const short* __restrict__ p, char* sm, int t) {
  const int r = t >> 3, seg = t & 7;
  const int4* s = (const int4*)(p + (size_t)r * C + seg * 32);
#pragma unroll
  for (int i = 0; i < 4; ++i) {
    const int kb = (seg * 32 + i * 8) * 2;
    *(int4*)(sm + r * 512 + (kb ^ ((r & 7) << 4))) = s[i];
  }
}

__device__ __forceinline__ short8v ldsA(const char* sm, int lane, int rt, int ks) {
  const int row = rt * 16 + (lane & 15);
  const int kb  = ks * 64 + ((lane >> 4) << 4);
  const int4 v = *(const int4*)(sm + row * 512 + (kb ^ ((row & 7) << 4)));
  union { int4 i; short8v s; } u; u.i = v; return u.s;
}

#define MFMA __builtin_amdgcn_mfma_f32_16x16x32_bf16

// ---------------------------------------------------------------------------
// GEMM body shared by valproj/outproj (proven in R10)
// ---------------------------------------------------------------------------
#define GEMM_BODY(WP)                                                       \
  short8v a[2][8];                                                          \
  _Pragma("unroll") for (int rt = 0; rt < 2; ++rt)                          \
  _Pragma("unroll") for (int ks = 0; ks < 8; ++ks)                          \
      a[rt][ks] = ldsA(smA, lane, rt, ks);                                  \
  f32x4 acc[2][4];                                                          \
  _Pragma("unroll") for (int rt = 0; rt < 2; ++rt)                          \
  _Pragma("unroll") for (int ct = 0; ct < 4; ++ct)                          \
      acc[rt][ct] = (f32x4){0.f, 0.f, 0.f, 0.f};                            \
  short8v b0[8], b1[8];                                                     \
  _Pragma("unroll") for (int ks = 0; ks < 8; ++ks)                          \
      b0[ks] = ldBP(WP, 16, cg0 + 0, ks, lane);                             \
  _Pragma("unroll") for (int ks = 0; ks < 8; ++ks)                          \
      b1[ks] = ldBP(WP, 16, cg0 + 1, ks, lane);                             \
  _Pragma("unroll") for (int ks = 0; ks < 8; ++ks) {                        \
    acc[0][0] = MFMA(a[0][ks], b0[ks], acc[0][0], 0, 0, 0);                 \
    acc[1][0] = MFMA(a[1][ks], b0[ks], acc[1][0], 0, 0, 0);                 \
  }                                                                         \
  _Pragma("unroll") for (int ks = 0; ks < 8; ++ks)                          \
      b0[ks] = ldBP(WP, 16, cg0 + 2, ks, lane);                             \
  _Pragma("unroll") for (int ks = 0; ks < 8; ++ks) {                        \
    acc[0][1] = MFMA(a[0][ks], b1[ks], acc[0][1], 0, 0, 0);                 \
    acc[1][1] = MFMA(a[1][ks], b1[ks], acc[1][1], 0, 0, 0);                 \
  }                                                                         \
  _Pragma("unroll") for (int ks = 0; ks < 8; ++ks)                          \
      b1[ks] = ldBP(WP, 16, cg0 + 3, ks, lane);                             \
  _Pragma("unroll") for (int ks = 0; ks < 8; ++ks) {                        \
    acc[0][2] = MFMA(a[0][ks], b0[ks], acc[0][2], 0, 0, 0);                 \
    acc[1][2] = MFMA(a[1][ks], b0[ks], acc[1][2], 0, 0, 0);                 \
  }                                                                         \
  _Pragma("unroll") for (int ks = 0; ks < 8; ++ks) {                        \
    acc[0][3] = MFMA(a[0][ks], b1[ks], acc[0][3], 0, 0, 0);                 \
    acc[1][3] = MFMA(a[1][ks], b1[ks], acc[1][3], 0, 0, 0);                 \
  }

// ---------------------------------------------------------------------------
// Kernel: value = bf16mm(input_flatten, WvP) + bv -> fp16 value[slice][padpix][d]
// ---------------------------------------------------------------------------
__global__ __launch_bounds__(256, 2) void k_valproj(
    const float* __restrict__ infl, const short* __restrict__ WvP,
    const float* __restrict__ bv, __half* __restrict__ value) {
  __shared__ __align__(16) char smA[16384];
  const int t = threadIdx.x, lane = t & 63, w = t >> 6;
  const int r0 = blockIdx.x * 32;
  stage_cast(infl + (size_t)r0 * C, smA, t);
  __syncthreads();
  const int cg0 = w * 4;
  const int lr = lane & 15, lk = lane >> 4;
  GEMM_BODY(WvP)

  const int n = (blockIdx.x >= (LEN / 32)) ? 1 : 0;
  const int pixbase = r0 - n * LEN;

  int pidx8[2][4];
#pragma unroll
  for (int rt = 0; rt < 2; ++rt)
#pragma unroll
    for (int r = 0; r < 4; ++r) {
      const int pix = pixbase + rt * 16 + lk * 4 + r;
      int pi;
      if (pix < 16384)      { const int y = pix >> 7;           pi = (y + 1) * 130 + (pix & 127) + 1; }
      else if (pix < 20480) { const int y = (pix - 16384) >> 6; pi = 16900 + (y + 1) * 66 + (pix & 63) + 1; }
      else if (pix < 21504) { const int y = (pix - 20480) >> 5; pi = 21256 + (y + 1) * 34 + (pix & 31) + 1; }
      else                  { const int y = (pix - 21504) >> 4; pi = 22412 + (y + 1) * 18 + (pix & 15) + 1; }
      pidx8[rt][r] = pi;
    }

#pragma unroll
  for (int ct = 0; ct < 4; ++ct) {
    const int col = (cg0 + ct) * 16 + lr;
    const float bb = bv[col];
    const int m = col >> 5, d = col & 31;
    __half* vp = value + ((size_t)(n * 8 + m) * PADPIX) * 32 + d;
#pragma unroll
    for (int rt = 0; rt < 2; ++rt)
#pragma unroll
      for (int r = 0; r < 4; ++r)
        vp[(size_t)pidx8[rt][r] * 32] = __float2half(acc[rt][ct][r] + bb);
  }
}

// ---------------------------------------------------------------------------
// Kernel: out = bf16mm(accB, WoP) + bo (fp32 out)
// ---------------------------------------------------------------------------
__global__ __launch_bounds__(256, 2) void k_outproj(
    const short* __restrict__ accB, const short* __restrict__ WoP,
    const float* __restrict__ bo, float* __restrict__ out) {
  __shared__ __align__(16) char smA[16384];
  const int t = threadIdx.x, lane = t & 63, w = t >> 6;
  const int r0 = blockIdx.x * 32;
  stage_bf16(accB + (size_t)r0 * C, smA, t);
  __syncthreads();
  const int cg0 = w * 4;
  const int lr = lane & 15, lk = lane >> 4;
  GEMM_BODY(WoP)

#pragma unroll
  for (int ct = 0; ct < 4; ++ct) {
    const int col = (cg0 + ct) * 16 + lr;
    const float bb = bo[col];
#pragma unroll
    for (int rt = 0; rt < 2; ++rt)
#pragma unroll
      for (int r = 0; r < 4; ++r) {
        const int row = r0 + rt * 16 + lk * 4 + r;
        out[(size_t)row * C + col] = acc[rt][ct][r] + bb;
      }
  }
}

// ---------------------------------------------------------------------------
// Kernel: offsets/attn GEMM + softmax + 8B fixed-point descriptor build
// descD[((n*8+m)*LEN + q)*16 + j] : uint2 {xfix|(yfix<<16), aw_half}
// fixed point: (coord + 1) * 128 with coord clamped to [-1, W] (per level).
// ---------------------------------------------------------------------------
__global__ __launch_bounds__(256, 3) void k_desc(
    const float* __restrict__ query, const float* __restrict__ refp,
    const short* __restrict__ WdP, const float* __restrict__ boff,
    const float* __restrict__ battn, uint2* __restrict__ descD) {
  __shared__ __align__(16) char smem[50176];
  char*  smA  = smem;                       // [32][512] bf16 A-tile
  float* offs = (float*)smem;               // [32][256] (aliases smA; used later)
  float* attw = (float*)(smem + 32768);     // [32][128]
  float* refs = (float*)(smem + 49152);     // [32][8]

  const int t = threadIdx.x, lane = t & 63, w = t >> 6;
  const int n   = blockIdx.x / 680;
  const int q0c = (blockIdx.x % 680) * 32;
  const size_t qrow = (size_t)n * LEN + q0c;

  refs[t] = refp[qrow * 8 + t];
  stage_cast(query + qrow * C, smA, t);
  __syncthreads();

  f32x4 acc[2][6];
#pragma unroll
  for (int a = 0; a < 2; ++a)
#pragma unroll
    for (int b = 0; b < 6; ++b) acc[a][b] = (f32x4){0.f, 0.f, 0.f, 0.f};
  const int cgb = w * 6;
#pragma unroll
  for (int ks = 0; ks < 8; ++ks) {
    const short8v a0 = ldsA(smA, lane, 0, ks);
    const short8v a1 = ldsA(smA, lane, 1, ks);
#pragma unroll
    for (int ct = 0; ct < 6; ++ct) {
      const short8v b = ldBP(WdP, 24, cgb + ct, ks, lane);
      acc[0][ct] = MFMA(a0, b, acc[0][ct], 0, 0, 0);
      acc[1][ct] = MFMA(a1, b, acc[1][ct], 0, 0, 0);
    }
  }
  __syncthreads();   // all LDS A reads complete before aliasing writes

#pragma unroll
  for (int ct = 0; ct < 6; ++ct) {
    const int col = (cgb + ct) * 16 + (lane & 15);
    const float bb = (col < 256) ? boff[col] : battn[col - 256];
#pragma unroll
    for (int rt = 0; rt < 2; ++rt)
#pragma unroll
      for (int r = 0; r < 4; ++r) {
        const int row = rt * 16 + ((lane >> 4) << 2) + r;
        const float vv = acc[rt][ct][r] + bb;
        if (col < 256) offs[row * 256 + col] = vv;
        else           attw[row * 128 + col - 256] = vv;
      }
  }
  __syncthreads();

  // softmax over 16 per (q, m): 256 tasks
  {
    const int q = t >> 3, m = t & 7;
    float v[16], mx = -1e30f;
#pragma unroll
    for (int j = 0; j < 16; ++j) { v[j] = attw[q * 128 + m * 16 + j]; mx = fmaxf(mx, v[j]); }
    float s = 0.f;
#pragma unroll
    for (int j = 0; j < 16; ++j) { v[j] = __expf(v[j] - mx); s += v[j]; }
    const float inv = 1.f / s;
#pragma unroll
    for (int j = 0; j < 16; ++j) attw[q * 128 + m * 16 + j] = v[j] * inv;
  }
  __syncthreads();

  // descriptor build: 32 q x 128 (m,j) = 4096, 16 per thread, coalesced
#pragma unroll
  for (int i = 0; i < 16; ++i) {
    const int e = i * 256 + t;
    const int q = e >> 7, rem = e & 127;
    const int m = rem >> 4, j = rem & 15, l = j >> 2;
    const int jo = m * 16 + j;
    const float ox = offs[q * 256 + 2 * jo], oy = offs[q * 256 + 2 * jo + 1];
    const float aw = attw[q * 128 + jo];
    const float rx = refs[q * 8 + l * 2 + 0], ry = refs[q * 8 + l * 2 + 1];
    const int W = 128 >> l;
    const float fW = (float)W;
    const float x = rx * fW + ox - 0.5f;
    const float y = ry * fW + oy - 0.5f;
    const float xc = fminf(fmaxf(x, -1.f), fW);
    const float yc = fminf(fmaxf(y, -1.f), fW);
    const uint32_t xfix = (uint32_t)((xc + 1.f) * 128.f + 0.5f);
    const uint32_t yfix = (uint32_t)((yc + 1.f) * 128.f + 0.5f);
    uint2 dsc;
    dsc.x = xfix | (yfix << 16);
    dsc.y = (uint32_t)__half_as_ushort(__float2half_rn(aw));
    descD[((size_t)(n * 8 + m) * LEN + q0c + q) * 16 + j] = dsc;
  }
}

// ---------------------------------------------------------------------------
// Kernel: cross-group pipelined gather over PADDED levels — no border logic.
// ---------------------------------------------------------------------------
__global__ __launch_bounds__(256, 4) void k_gather(
    const uint2* __restrict__ descD, const __half* __restrict__ value,
    short* __restrict__ accB) {
  const int t = threadIdx.x;
  const int d4 = t & 3, ql = t >> 2;          // 64 queries per block
  const int bid = blockIdx.x;
  const int s = bid & 15, qc = bid >> 4;      // slice, query-chunk (340)
  const int n = s >> 3, m = s & 7;
  const int q = qc * 64 + ql;
  const uint4* dp4 = (const uint4*)(descD + ((size_t)(n * 8 + m) * LEN + q) * 16);
  const char* vb = (const char*)value +
                   (size_t)((n * 8 + m)) * PADPIX * 64 + d4 * 16;

  uint4 dd[8];
#pragma unroll
  for (int i = 0; i < 8; ++i) dd[i] = dp4[i];
  __builtin_amdgcn_sched_barrier(0);

  float accf[8];
#pragma unroll
  for (int i = 0; i < 8; ++i) accf[i] = 0.f;

  union V { uint4 v; __half2 h[4]; };
  V rA[8], rB[8];
  __half2 hwA[8], hwB[8];

#define DECJ(G, ODD, R, HW, BASE)                                             \
  {                                                                           \
    constexpr int l_ = (G) >> 1;                                              \
    constexpr int W_ = 128 >> l_;                                             \
    constexpr int Wp_ = W_ + 2;                                               \
    constexpr int stp_ = (l_ == 0) ? 0 : (l_ == 1) ? 16900 : (l_ == 2) ? 21256 : 22412; \
    const uint32_t lo_ = (ODD) ? dd[G].z : dd[G].x;                           \
    const uint32_t hi_ = (ODD) ? dd[G].w : dd[G].y;                           \
    const int xf_ = (int)(lo_ & 0xffffu), yf_ = (int)(lo_ >> 16);             \
    const float aw_ = __half2float(__ushort_as_half((unsigned short)(hi_ & 0xffffu))); \
    const int xi_ = xf_ >> 7, yi_ = yf_ >> 7;                                 \
    const float fx_ = (float)(xf_ & 127) * 0.0078125f;                        \
    const float fy_ = (float)(yf_ & 127) * 0.0078125f;                        \
    const float wx0_ = 1.f - fx_;                                             \
    const float wy0a_ = (1.f - fy_) * aw_;                                    \
    const float wy1a_ = fy_ * aw_;                                            \
    HW[(BASE) + 0] = __float2half2_rn(wx0_ * wy0a_);                          \
    HW[(BASE) + 1] = __float2half2_rn(fx_ * wy0a_);                           \
    HW[(BASE) + 2] = __float2half2_rn(wx0_ * wy1a_);                          \
    HW[(BASE) + 3] = __float2half2_rn(fx_ * wy1a_);                           \
    const char* a0_ = vb + (size_t)(stp_ + yi_ * Wp_ + xi_) * 64u;            \
    const char* a1_ = a0_ + Wp_ * 64;                                         \
    R[(BASE) + 0].v = *(const uint4*)(a0_);                                   \
    R[(BASE) + 1].v = *(const uint4*)(a0_ + 64);                              \
    R[(BASE) + 2].v = *(const uint4*)(a1_);                                   \
    R[(BASE) + 3].v = *(const uint4*)(a1_ + 64);                              \
  }

#define DECG(G, R, HW)                                                        \
  DECJ(G, 0, R, HW, 0)                                                        \
  DECJ(G, 1, R, HW, 4)                                                        \
  __builtin_amdgcn_sched_barrier(0);

#define CONSG(R, HW)                                                          \
  {                                                                           \
    __half2 acch[4];                                                          \
    _Pragma("unroll") for (int i_ = 0; i_ < 4; ++i_)                          \
        acch[i_] = __float2half2_rn(0.f);                                     \
    _Pragma("unroll") for (int c_ = 0; c_ < 8; ++c_) {                        \
      _Pragma("unroll") for (int i_ = 0; i_ < 4; ++i_)                        \
          acch[i_] = __hfma2(R[c_].h[i_], HW[c_], acch[i_]);                  \
    }                                                                         \
    _Pragma("unroll") for (int i_ = 0; i_ < 4; ++i_) {                        \
      const float2 f_ = __half22float2(acch[i_]);                             \
      accf[2 * i_] += f_.x; accf[2 * i_ + 1] += f_.y;                         \
    }                                                                         \
  }

  DECG(0, rA, hwA)
  DECG(1, rB, hwB)
  CONSG(rA, hwA)
  DECG(2, rA, hwA)
  CONSG(rB, hwB)
  DECG(3, rB, hwB)
  CONSG(rA, hwA)
  DECG(4, rA, hwA)
  CONSG(rB, hwB)
  DECG(5, rB, hwB)
  CONSG(rA, hwA)
  DECG(6, rA, hwA)
  CONSG(rB, hwB)
  DECG(7, rB, hwB)
  CONSG(rA, hwA)
  CONSG(rB, hwB)
#undef DECJ
#undef DECG
#undef CONSG

  short8v o;
#pragma unroll
  for (int i = 0; i < 8; ++i) o[i] = f2bf(accf[i]);
  *(short8v*)(accB + ((size_t)n * LEN + q) * 256 + m * 32 + d4 * 8) = o;
}

// ---------------------------------------------------------------------------
extern "C" void kernel_launch(void* const* d_in, const int* in_sizes, int n_in,
                              void* d_out, int out_size, void* d_ws, size_t ws_size,
                              hipStream_t stream) {
  const float* query = (const float*)d_in[0];
  const float* refp  = (const float*)d_in[1];
  const float* infl  = (const float*)d_in[2];
  const float* Woff  = (const float*)d_in[3];
  const float* boff  = (const float*)d_in[4];
  const float* Wattn = (const float*)d_in[5];
  const float* battn = (const float*)d_in[6];
  const float* Wval  = (const float*)d_in[7];
  const float* bval  = (const float*)d_in[8];
  const float* Wout  = (const float*)d_in[9];
  const float* bout  = (const float*)d_in[10];
  float* out = (float*)d_out;

  char* ws = (char*)d_ws;
  __half* value = (__half*)ws;                   // 16*22736*64 = 23,281,664 B
  short*  accB  = (short*)(ws + 23281664);       // 22,282,240 B
  uint2*  desc8 = (uint2*)(ws + 45563904);       // 44,564,480 B (full LEN)
  short*  WvP   = (short*)(ws + 90128384);       // 131,072 B
  short*  WdP   = (short*)(ws + 90259456);       // 196,608 B
  short*  WoP   = (short*)(ws + 90456064);       // 131,072 B  (total 90.6 MB)

  k_wpack<<<dim3(384, 3), 256, 0, stream>>>(Wval, Woff, Wattn, Wout,
                                            WvP, WdP, WoP);
  k_zpad<<<dim3(16, 4), 256, 0, stream>>>(value);

  k_valproj<<<(NB * LEN) / 32, 256, 0, stream>>>(infl, WvP, bval, value);

  k_desc<<<NB * (LEN / 32), 256, 0, stream>>>(query, refp, WdP, boff, battn,
                                              desc8);
  k_gather<<<16 * (LEN / 64), 256, 0, stream>>>(desc8, value, accB);

  k_outproj<<<(NB * LEN) / 32, 256, 0, stream>>>(accB, WoP, bout, out);
}